// Round 3
// baseline (314.562 us; speedup 1.0000x reference)
//
#include <hip/hip_runtime.h>
#include <hip/hip_bf16.h>
#include <hip/hip_fp16.h>
#include <type_traits>

#define B_ 2
#define S_ 2048
#define D_ 2048
#define H_ 8
#define KV_ 2
#define HD_ 256
#define WINDOW_ 512
#define EPS_ 1e-6f
#define MASKV_ -30000.0f

typedef _Float16 f16;
typedef _Float16 half8 __attribute__((ext_vector_type(8)));
typedef _Float16 half2v __attribute__((ext_vector_type(2)));
typedef _Float16 half4v __attribute__((ext_vector_type(4)));
typedef float floatx4 __attribute__((ext_vector_type(4)));
typedef float floatx8 __attribute__((ext_vector_type(8)));
typedef float floatx16 __attribute__((ext_vector_type(16)));

#define GLOAD_LDS16(g, l)                                                        \
    __builtin_amdgcn_global_load_lds(                                            \
        (const __attribute__((address_space(1))) unsigned int*)(g),              \
        (__attribute__((address_space(3))) unsigned int*)(l), 16, 0, 0)

#define VMWAIT(n) asm volatile("s_waitcnt vmcnt(" #n ")" ::: "memory")

// ---------------------------------------------------------------------------
// prep: fp32->fp16 convert of x + all 4 weight transposes.  (round-0, proven)
// ---------------------------------------------------------------------------
__global__ __launch_bounds__(256) void prep(const float* __restrict__ x,
                                            const float* __restrict__ wq,
                                            const float* __restrict__ wk,
                                            const float* __restrict__ wv,
                                            const float* __restrict__ wo,
                                            f16* __restrict__ xh,
                                            f16* __restrict__ BT,
                                            f16* __restrict__ woT) {
    int bid = blockIdx.x;
    const int t = threadIdx.x;
    if (bid < 8192) {
        const int i = bid * 256 + t;
        float4 v = ((const float4*)x)[i];
        half4v hv = {(f16)v.x, (f16)v.y, (f16)v.z, (f16)v.w};
        ((half4v*)xh)[i] = hv;
        return;
    }
    bid -= 8192;
    const float* src;
    f16* dst;
    int C, bx, by;
    if (bid < 1024) {
        src = wq; dst = BT; C = 2048; bx = bid & 31; by = bid >> 5;
    } else if (bid < 1280) {
        const int b3 = bid - 1024;
        src = wk; dst = BT + (size_t)2048 * 2048; C = 512; bx = b3 & 7; by = b3 >> 3;
    } else if (bid < 1536) {
        const int b3 = bid - 1280;
        src = wv; dst = BT + (size_t)2560 * 2048; C = 512; bx = b3 & 7; by = b3 >> 3;
    } else {
        const int b3 = bid - 1536;
        src = wo; dst = woT; C = 2048; bx = b3 & 31; by = b3 >> 5;
    }
    __shared__ float tl[64][65];
    const int c0 = bx * 64, r0 = by * 64;
#pragma unroll
    for (int i = 0; i < 4; ++i) {
        const int idx = i * 256 + t;
        const int row = idx >> 4;
        const int c4 = (idx & 15) * 4;
        float4 v = *(const float4*)&src[(size_t)(r0 + row) * C + c0 + c4];
        tl[row][c4 + 0] = v.x; tl[row][c4 + 1] = v.y;
        tl[row][c4 + 2] = v.z; tl[row][c4 + 3] = v.w;
    }
    __syncthreads();
#pragma unroll
    for (int i = 0; i < 4; ++i) {
        const int idx = i * 256 + t;
        const int c = idx >> 4;
        const int r4 = (idx & 15) * 4;
        half4v hv = {(f16)tl[r4 + 0][c], (f16)tl[r4 + 1][c],
                     (f16)tl[r4 + 2][c], (f16)tl[r4 + 3][c]};
        *(half4v*)&dst[(size_t)(c0 + c) * 2048 + r0 + r4] = hv;
    }
}

// ---------------------------------------------------------------------------
// 2-phase fp16 MFMA GEMM (round-0, proven) — used for out-projection.
// ---------------------------------------------------------------------------
#define CH_ 528  // chunk stride in f16
template <typename OutT>
__global__ __launch_bounds__(256) void gemm_f16(const f16* __restrict__ A,
                                                const f16* __restrict__ BT,
                                                OutT* __restrict__ C,
                                                int M, int N, int K) {
    __shared__ __align__(16) f16 sA[16 * CH_];
    __shared__ __align__(16) f16 sB[16 * CH_];

    const int t = threadIdx.x;
    const int lane = t & 63;
    const int w = t >> 6;
    const int l31 = lane & 31, q1 = lane >> 5;
    const int m0 = blockIdx.y * 128, n0 = blockIdx.x * 128;
    const int mw = (w & 1) * 64, nw = (w >> 1) * 64;

    floatx16 acc[4];
#pragma unroll
    for (int i = 0; i < 4; ++i) acc[i] = (floatx16)(0.f);

    const int r8 = lane >> 3;
    const int g = (lane & 7) ^ r8;

    for (int k0 = 0; k0 < K; k0 += 64) {
#pragma unroll
        for (int cc = 0; cc < 4; ++cc) {
            const int chunk = w * 4 + cc;
            const int row = chunk * 8 + r8;
            GLOAD_LDS16(A + (size_t)(m0 + row) * K + k0 + g * 8,
                        sA + chunk * CH_ + lane * 8);
            GLOAD_LDS16(BT + (size_t)(n0 + row) * K + k0 + g * 8,
                        sB + chunk * CH_ + lane * 8);
        }
        __syncthreads();

#pragma unroll
        for (int ks = 0; ks < 4; ++ks) {
            const int G = ks * 2 + q1;
            half8 af[2], bf[2];
#pragma unroll
            for (int mt = 0; mt < 2; ++mt) {
                const int ra = mw + mt * 32 + l31;
                af[mt] = *(const half8*)(sA + (ra >> 3) * CH_ + (ra & 7) * 64 +
                                         (G ^ (ra & 7)) * 8);
                const int rb = nw + mt * 32 + l31;
                bf[mt] = *(const half8*)(sB + (rb >> 3) * CH_ + (rb & 7) * 64 +
                                         (G ^ (rb & 7)) * 8);
            }
#pragma unroll
            for (int mt = 0; mt < 2; ++mt)
#pragma unroll
                for (int nt = 0; nt < 2; ++nt)
                    acc[mt * 2 + nt] = __builtin_amdgcn_mfma_f32_32x32x16_f16(
                        af[mt], bf[nt], acc[mt * 2 + nt], 0, 0, 0);
        }
        __syncthreads();
    }

#pragma unroll
    for (int mt = 0; mt < 2; ++mt)
#pragma unroll
        for (int nt = 0; nt < 2; ++nt)
#pragma unroll
            for (int r = 0; r < 16; ++r) {
                const int row = m0 + mw + mt * 32 + (r & 3) + 8 * (r >> 2) + 4 * q1;
                const int col = n0 + nw + nt * 32 + l31;
                C[(size_t)row * N + col] = (OutT)acc[mt * 2 + nt][r];
            }
}

// ---------------------------------------------------------------------------
// 8-phase 256x256 MFMA GEMM, v2: fragment-reuse + 32x32x16 MFMA.
//
// Per-wave output: 64x32 in each of 4 quadrants (qm,qn = M-half,N-half of the
// 256x256 tile).  Quadrant phase order (0,0)->(0,1)->(1,1)->(1,0) so each
// phase reads only the NEW operand half:
//   ph0: read a0 (8) + b0 (4)   MFMA q(0,0)      [12 ds_read_b128]
//   ph1: read b1 (4)            MFMA q(0,1)      [a0 held]
//   ph2: read a1 (8)            MFMA q(1,1)      [b1 held]
//   ph3: re-read b0 (4)         MFMA q(1,0)      [a1 held]
// 28 reads/wave/tile (was 48) -> LDS 2304 cy/tile < prior 3072; MFMA via
// 32x32x16 (2495 TF ceiling): 8 MFMA/phase.
//
// Staging: one half-tile per phase, issue order = first-use order A0,B0,B1,A1.
// 4-slot ring per operand (slot=(2T+half)&3): T+1's stagings never touch the
// slots tile T reads.  vmcnt ledger (2 loads/staging): steady state vmcnt(4)
// before ph0/ph1/ph2 guarantees exactly the half each phase reads while the
// newest 2 stagings stay in flight; ph3 reads only already-guaranteed data.
// Tail drains 4 -> 2 -> 0.  Barrier AFTER each wave's vmcnt transfers
// completion across waves.
//
// LDS swizzle (measured 0 conflicts): slot q of row r holds global k-slot
// q^(r&7) (pre-swizzled GLOBAL source, linear global_load_lds dest); reads
// use slot (ks*2+q1)^(l31&7).
// A/B frag (32x32x16): m(n)=lane&31, k=(lane>>5)*8+j.  C/D: col=lane&31,
// row=(reg&3)+8*(reg>>2)+4*(lane>>5)  [m74/m101-verified, round-0-proven].
// ---------------------------------------------------------------------------
template <typename OutT>
__global__ __launch_bounds__(512, 2) void gemm_8p(const f16* __restrict__ A,
                                                  const f16* __restrict__ BT,
                                                  OutT* __restrict__ C,
                                                  int M, int N, int K) {
    __shared__ __align__(16) f16 sAA[4 * 8192];  // 64 KB: 4 half-slots, 128x64
    __shared__ __align__(16) f16 sBB[4 * 8192];  // 64 KB

    const int tid = threadIdx.x;
    const int lane = tid & 63, w = tid >> 6;
    const int l31 = lane & 31, q1 = lane >> 5;
    const int w1 = w & 1, w2 = w >> 1;
    const int m0 = blockIdx.y * 256, n0 = blockIdx.x * 256;

    // staging: thread covers LDS bytes tid*16 and tid*16+8192 of a half.
    const int kx = ((tid & 7) ^ ((tid >> 3) & 7)) * 8;   // pre-swizzled src k
    const f16* srcA0 = A + (size_t)(m0 + (tid >> 3)) * K;
    const f16* srcB0 = BT + (size_t)(n0 + (tid >> 3)) * K;
    f16* dstA0 = sAA + tid * 8;
    f16* dstB0 = sBB + tid * 8;

    auto stageA = [&](int half, int kt) {
        const int slot = (2 * kt + half) & 3;
        const f16* s = srcA0 + (size_t)(half * 128) * K + kt * 64 + kx;
        f16* d = dstA0 + slot * 8192;
        GLOAD_LDS16(s, d);
        GLOAD_LDS16(s + (size_t)64 * K, d + 4096);
    };
    auto stageB = [&](int half, int kt) {
        const int slot = (2 * kt + half) & 3;
        const f16* s = srcB0 + (size_t)(half * 128) * K + kt * 64 + kx;
        f16* d = dstB0 + slot * 8192;
        GLOAD_LDS16(s, d);
        GLOAD_LDS16(s + (size_t)64 * K, d + 4096);
    };

    // fragment-read offsets (f16 units): row_local*64 + slot_xor*8
    const int arow = (w1 * 64 + l31) * 64;   // + mt*2048
    const int brow = (w2 * 32 + l31) * 64;
    int xk[4];
#pragma unroll
    for (int ks = 0; ks < 4; ++ks) xk[ks] = ((ks * 2 + q1) ^ (l31 & 7)) * 8;

    // acc[p][mt]: p = quadrant in phase order (0,0),(0,1),(1,1),(1,0)
    floatx16 acc[4][2];
#pragma unroll
    for (int p = 0; p < 4; ++p)
#pragma unroll
        for (int mt = 0; mt < 2; ++mt) acc[p][mt] = (floatx16)(0.f);

    int st = 0;  // tile T's slot base (0 or 2); half h of T at slot st+h

    const int NT = K >> 6;  // K / 64

    // prologue: tile 0's stagings in first-use order A0,B0,B1,A1
    stageA(0, 0); stageB(0, 0); stageB(1, 0); stageA(1, 0);

    auto tile = [&](auto LASTC, int T) {
        constexpr bool LAST = decltype(LASTC)::value;
        const f16* a0p = sAA + (size_t)(st + 0) * 8192;
        const f16* a1p = sAA + (size_t)(st + 1) * 8192;
        const f16* b0p = sBB + (size_t)(st + 0) * 8192;
        const f16* b1p = sBB + (size_t)(st + 1) * 8192;
        half8 a0[2][4], a1[2][4], bf[4];

        // ---- ph0: quadrant (0,0) = a0 x b0 ----
        VMWAIT(4);
        __builtin_amdgcn_s_barrier();
#pragma unroll
        for (int mt = 0; mt < 2; ++mt)
#pragma unroll
            for (int ks = 0; ks < 4; ++ks)
                a0[mt][ks] = *(const half8*)(a0p + arow + mt * 2048 + xk[ks]);
#pragma unroll
        for (int ks = 0; ks < 4; ++ks)
            bf[ks] = *(const half8*)(b0p + brow + xk[ks]);
        if constexpr (!LAST) stageA(0, T + 1);
        __builtin_amdgcn_s_setprio(1);
#pragma unroll
        for (int ks = 0; ks < 4; ++ks)
#pragma unroll
            for (int mt = 0; mt < 2; ++mt)
                acc[0][mt] = __builtin_amdgcn_mfma_f32_32x32x16_f16(
                    a0[mt][ks], bf[ks], acc[0][mt], 0, 0, 0);
        __builtin_amdgcn_s_setprio(0);

        // ---- ph1: quadrant (0,1) = a0 x b1 ----
        if constexpr (!LAST) VMWAIT(4); else VMWAIT(2);
        __builtin_amdgcn_s_barrier();
#pragma unroll
        for (int ks = 0; ks < 4; ++ks)
            bf[ks] = *(const half8*)(b1p + brow + xk[ks]);
        if constexpr (!LAST) stageB(0, T + 1);
        __builtin_amdgcn_s_setprio(1);
#pragma unroll
        for (int ks = 0; ks < 4; ++ks)
#pragma unroll
            for (int mt = 0; mt < 2; ++mt)
                acc[1][mt] = __builtin_amdgcn_mfma_f32_32x32x16_f16(
                    a0[mt][ks], bf[ks], acc[1][mt], 0, 0, 0);
        __builtin_amdgcn_s_setprio(0);

        // ---- ph2: quadrant (1,1) = a1 x b1 ----
        if constexpr (!LAST) VMWAIT(4); else VMWAIT(0);
        __builtin_amdgcn_s_barrier();
#pragma unroll
        for (int mt = 0; mt < 2; ++mt)
#pragma unroll
            for (int ks = 0; ks < 4; ++ks)
                a1[mt][ks] = *(const half8*)(a1p + arow + mt * 2048 + xk[ks]);
        if constexpr (!LAST) stageB(1, T + 1);
        __builtin_amdgcn_s_setprio(1);
#pragma unroll
        for (int ks = 0; ks < 4; ++ks)
#pragma unroll
            for (int mt = 0; mt < 2; ++mt)
                acc[2][mt] = __builtin_amdgcn_mfma_f32_32x32x16_f16(
                    a1[mt][ks], bf[ks], acc[2][mt], 0, 0, 0);
        __builtin_amdgcn_s_setprio(0);

        // ---- ph3: quadrant (1,0) = a1 x b0 (re-read) ----
        __builtin_amdgcn_s_barrier();
#pragma unroll
        for (int ks = 0; ks < 4; ++ks)
            bf[ks] = *(const half8*)(b0p + brow + xk[ks]);
        if constexpr (!LAST) stageA(1, T + 1);
        __builtin_amdgcn_s_setprio(1);
#pragma unroll
        for (int ks = 0; ks < 4; ++ks)
#pragma unroll
            for (int mt = 0; mt < 2; ++mt)
                acc[3][mt] = __builtin_amdgcn_mfma_f32_32x32x16_f16(
                    a1[mt][ks], bf[ks], acc[3][mt], 0, 0, 0);
        __builtin_amdgcn_s_setprio(0);
    };

    for (int T = 0; T < NT - 1; ++T) {
        tile(std::false_type{}, T);
        st ^= 2;
    }
    tile(std::true_type{}, NT - 1);

    // epilogue: quadrant p -> (qm,qn); 32x32 C/D layout (round-0-proven)
    const int qmv[4] = {0, 0, 1, 1};
    const int qnv[4] = {0, 1, 1, 0};
#pragma unroll
    for (int p = 0; p < 4; ++p) {
        const int rb = m0 + qmv[p] * 128 + w1 * 64;
        const int cb = n0 + qnv[p] * 128 + w2 * 32 + l31;
#pragma unroll
        for (int mt = 0; mt < 2; ++mt)
#pragma unroll
            for (int r = 0; r < 16; ++r) {
                const int row = rb + mt * 32 + (r & 3) + 8 * (r >> 2) + 4 * q1;
                C[(size_t)row * N + cb] = (OutT)acc[p][mt][r];
            }
    }
}

// ---------------------------------------------------------------------------
// K/V norm kernel (round-0, proven).
// ---------------------------------------------------------------------------
#define NRBK_ ((B_ * S_ * KV_) / 4)  // 2048 blocks, 4 waves each

__global__ __launch_bounds__(256) void norm_kv_f16(
    const f16* __restrict__ QKVh, f16* __restrict__ Kh, f16* __restrict__ Vt,
    const float* __restrict__ cosb, const float* __restrict__ sinb,
    const float* __restrict__ kw) {
    __shared__ f16 vt[64][266];

    const int w = threadIdx.x >> 6, lane = threadIdx.x & 63;

    if (blockIdx.x < NRBK_) {
        const int wid = blockIdx.x * 4 + w;
        const int d0 = lane * 2;
        const int b = wid / (S_ * KV_);
        const int r = wid % (S_ * KV_);
        const int s = r / KV_, kv = r % KV_;
        const f16* p = QKVh + (size_t)(b * S_ + s) * 3072 + 2048 + kv * HD_;
        half2v lo = *(const half2v*)(p + d0);
        half2v hi = *(const half2v*)(p + 128 + d0);
        float x0 = (float)lo[0], x1 = (float)lo[1], x2 = (float)hi[0], x3 = (float)hi[1];
        float ss = x0 * x0 + x1 * x1 + x2 * x2 + x3 * x3;
#pragma unroll
        for (int off = 32; off >= 1; off >>= 1) ss += __shfl_xor(ss, off);
        const float inv = rsqrtf(ss * (1.0f / HD_) + EPS_);
        float2 wlo = *(const float2*)(kw + d0), whi = *(const float2*)(kw + 128 + d0);
        float y0 = x0 * inv * wlo.x, y1 = x1 * inv * wlo.y;
        float y2 = x2 * inv * whi.x, y3 = x3 * inv * whi.y;
        const float* cb = cosb + (size_t)(b * S_ + s) * HD_;
        const float* sb = sinb + (size_t)(b * S_ + s) * HD_;
        float2 clo = *(const float2*)(cb + d0), chi = *(const float2*)(cb + 128 + d0);
        float2 slo = *(const float2*)(sb + d0), shi = *(const float2*)(sb + 128 + d0);
        half2v olo = {(f16)(y0 * clo.x - y2 * slo.x), (f16)(y1 * clo.y - y3 * slo.y)};
        half2v ohi = {(f16)(y2 * chi.x + y0 * shi.x), (f16)(y3 * chi.y + y1 * shi.y)};
        f16* d = Kh + ((size_t)(b * KV_ + kv) * S_ + s) * HD_;
        *(half2v*)(d + d0) = olo;
        *(half2v*)(d + 128 + d0) = ohi;
        return;
    }

    const int vb = blockIdx.x - NRBK_;
    const int s0 = (vb & 31) * 64;
    const int kv = (vb >> 5) & 1;
    const int b  = vb >> 6;

    for (int r = 0; r < 16; ++r) {
        const int sl = w * 16 + r;
        const f16* p = QKVh + (size_t)(b * S_ + s0 + sl) * 3072 + 2560 + kv * HD_;
        const int d0 = lane * 2;
        half2v lo = *(const half2v*)(p + d0);
        half2v hi = *(const half2v*)(p + 128 + d0);
        float x0 = (float)lo[0], x1 = (float)lo[1], x2 = (float)hi[0], x3 = (float)hi[1];
        float ss = x0 * x0 + x1 * x1 + x2 * x2 + x3 * x3;
#pragma unroll
        for (int off = 32; off >= 1; off >>= 1) ss += __shfl_xor(ss, off);
        const float inv = rsqrtf(ss * (1.0f / HD_) + EPS_);
        half2v olo = {(f16)(x0 * inv), (f16)(x1 * inv)};
        half2v ohi = {(f16)(x2 * inv), (f16)(x3 * inv)};
        *(half2v*)&vt[sl][d0] = olo;
        *(half2v*)&vt[sl][128 + d0] = ohi;
    }
    __syncthreads();
    f16* dst = Vt + (size_t)(b * KV_ + kv) * HD_ * S_;
    for (int i = 0; i < 64; ++i) {
        const int dd = w * 64 + i;
        dst[(size_t)dd * S_ + s0 + lane] = vt[lane][dd];
    }
}

// ---------------------------------------------------------------------------
// MFMA flash attention (round-0, proven). 128 q, 8 waves, dbuf staging.
// ---------------------------------------------------------------------------
__global__ __launch_bounds__(512, 2) void attn_mfma(const f16* __restrict__ QKVh,
                                                    const f16* __restrict__ Kh,
                                                    const f16* __restrict__ Vt,
                                                    f16* __restrict__ attnh,
                                                    const float* __restrict__ cosb,
                                                    const float* __restrict__ sinb,
                                                    const float* __restrict__ qw) {
    __shared__ __align__(16) f16 sK[2][64 * 256];
    __shared__ __align__(16) f16 sV[2][256 * 64];
    __shared__ __align__(16) f16 sP[8][16 * 72];

    const int qt = blockIdx.x, h = blockIdx.y, b = blockIdx.z;
    const int kvh = h / (H_ / KV_);
    const int t = threadIdx.x, lane = t & 63, w = t >> 6;
    const int i16 = lane & 15, q4 = lane >> 4;

    const int qrow = qt * 128 + w * 16 + i16;
    const f16* qbase = QKVh + (size_t)(b * S_ + qrow) * 3072 + h * HD_ + q4 * 8;
    half8 qf[8];
#pragma unroll
    for (int kk = 0; kk < 8; ++kk) qf[kk] = *(const half8*)(qbase + kk * 32);

    {
        float ss = 0.f;
#pragma unroll
        for (int kk = 0; kk < 8; ++kk)
#pragma unroll
            for (int j = 0; j < 8; ++j) {
                const float v = (float)qf[kk][j];
                ss += v * v;
            }
        ss += __shfl_xor(ss, 16);
        ss += __shfl_xor(ss, 32);
        const float inv = rsqrtf(ss * (1.0f / HD_) + EPS_);
        const float* cb = cosb + (size_t)(b * S_ + qrow) * HD_ + q4 * 8;
        const float* sb = sinb + (size_t)(b * S_ + qrow) * HD_ + q4 * 8;
        const float* wp = qw + q4 * 8;
#pragma unroll
        for (int kk = 0; kk < 4; ++kk) {
            const int dl = kk * 32, dh = dl + 128;
            floatx8 cl = *(const floatx8*)(cb + dl);
            floatx8 ch = *(const floatx8*)(cb + dh);
            floatx8 sl = *(const floatx8*)(sb + dl);
            floatx8 sh = *(const floatx8*)(sb + dh);
            floatx8 wl = *(const floatx8*)(wp + dl);
            floatx8 wh = *(const floatx8*)(wp + dh);
            half8 nl, nh;
#pragma unroll
            for (int j = 0; j < 8; ++j) {
                const float xl = (float)qf[kk][j] * inv * wl[j];
                const float xh = (float)qf[kk + 4][j] * inv * wh[j];
                nl[j] = (f16)(xl * cl[j] - xh * sl[j]);
                nh[j] = (f16)(xh * ch[j] + xl * sh[j]);
            }
            qf[kk] = nl;
            qf[kk + 4] = nh;
        }
    }

    floatx4 o[16];
#pragma unroll
    for (int i = 0; i < 16; ++i) o[i] = (floatx4){0.f, 0.f, 0.f, 0.f};
    float mrow[4] = {-1e30f, -1e30f, -1e30f, -1e30f};
    float lrow[4] = {0.f, 0.f, 0.f, 0.f};

    const size_t kbase = (size_t)(b * KV_ + kvh) * S_ * HD_;
    const size_t vbase = (size_t)(b * KV_ + kvh) * HD_ * S_;
    const int srow0 = qt * 128 + w * 16 + q4 * 4;

    const int kt_lo = (2 * qt - 8) > 0 ? (2 * qt - 8) : 0;
    const int kt_hi = 2 * qt + 1;
    const int s_lo_w = qt * 128 + w * 16;
    int ktw_lo = (s_lo_w - (WINDOW_ - 1)) >> 6;
    if (ktw_lo < kt_lo) ktw_lo = kt_lo;
    const int ktw_hi = (s_lo_w + 15) >> 6;

    auto stage = [&](int kt, int buf) {
#pragma unroll
        for (int c = 0; c < 4; ++c) {
            const int chunk = w * 4 + c;
            const int keyl = chunk * 2 + (lane >> 5);
            const int g = (lane & 31) ^ (keyl & 31);
            GLOAD_LDS16(Kh + kbase + (size_t)(kt * 64 + keyl) * HD_ + g * 8,
                        sK[buf] + chunk * 512 + lane * 8);
            const int diml = chunk * 8 + (lane >> 3);
            const int g2 = (lane & 7) ^ (diml & 7);
            GLOAD_LDS16(Vt + vbase + (size_t)diml * S_ + kt * 64 + g2 * 8,
                        sV[buf] + chunk * 512 + lane * 8);
        }
    };

    stage(kt_lo, 0);
    int cur = 0;
    for (int kt = kt_lo; kt <= kt_hi; ++kt, cur ^= 1) {
        __syncthreads();
        if (kt < kt_hi) stage(kt + 1, cur ^ 1);
        if (kt < ktw_lo || kt > ktw_hi) continue;

        const f16* sKc = sK[cur];
        const f16* sVc = sV[cur];

        floatx4 sc[4];
#pragma unroll
        for (int nt = 0; nt < 4; ++nt) sc[nt] = (floatx4){0.f, 0.f, 0.f, 0.f};
#pragma unroll
        for (int ks = 0; ks < 8; ++ks)
#pragma unroll
            for (int nt = 0; nt < 4; ++nt) {
                const int keyl = nt * 16 + i16;
                const int gp = (ks * 4 + q4) ^ (keyl & 31);
                half8 kf = *(const half8*)(sKc + keyl * 256 + gp * 8);
                sc[nt] = __builtin_amdgcn_mfma_f32_16x16x32_f16(qf[ks], kf, sc[nt], 0, 0, 0);
            }

#pragma unroll
        for (int r = 0; r < 4; ++r) {
            const int s = srow0 + r;
            float mx = -1e30f;
#pragma unroll
            for (int nt = 0; nt < 4; ++nt) {
                const int j = kt * 64 + nt * 16 + i16;
                const bool valid = (j <= s) && (s - j < WINDOW_);
                const float v = valid ? sc[nt][r] : MASKV_;
                sc[nt][r] = v;
                mx = fmaxf(mx, v);
            }
#pragma unroll
            for (int off = 1; off < 16; off <<= 1) mx = fmaxf(mx, __shfl_xor(mx, off));
            const float mnew = fmaxf(mrow[r], mx);
            const float alpha = __expf(mrow[r] - mnew);
            mrow[r] = mnew;
            float rs = 0.f;
#pragma unroll
            for (int nt = 0; nt < 4; ++nt) {
                const float p = __expf(sc[nt][r] - mnew);
                sc[nt][r] = p;
                rs += p;
            }
#pragma unroll
            for (int off = 1; off < 16; off <<= 1) rs += __shfl_xor(rs, off);
            lrow[r] = lrow[r] * alpha + rs;
#pragma unroll
            for (int nt2 = 0; nt2 < 16; ++nt2) o[nt2][r] *= alpha;
        }

        f16* sPw = sP[w];
#pragma unroll
        for (int nt = 0; nt < 4; ++nt)
#pragma unroll
            for (int r = 0; r < 4; ++r)
                sPw[(q4 * 4 + r) * 72 + nt * 16 + i16] = (f16)sc[nt][r];
        asm volatile("s_waitcnt lgkmcnt(0)" ::: "memory");

#pragma unroll
        for (int kt2 = 0; kt2 < 2; ++kt2) {
            half8 pf = *(const half8*)(sPw + i16 * 72 + kt2 * 32 + q4 * 8);
#pragma unroll
            for (int nt2 = 0; nt2 < 16; ++nt2) {
                const int dim = nt2 * 16 + i16;
                const int gp = (kt2 * 4 + q4) ^ (dim & 7);
                half8 vf = *(const half8*)(sVc + dim * 64 + gp * 8);
                o[nt2] = __builtin_amdgcn_mfma_f32_16x16x32_f16(pf, vf, o[nt2], 0, 0, 0);
            }
        }
    }

    float inv2[4];
#pragma unroll
    for (int r = 0; r < 4; ++r) inv2[r] = 1.0f / lrow[r];
    f16* ob = attnh + (size_t)(b * S_ + qt * 128 + w * 16) * (H_ * HD_) + h * HD_;
#pragma unroll
    for (int nt2 = 0; nt2 < 16; ++nt2)
#pragma unroll
        for (int r = 0; r < 4; ++r)
            ob[(size_t)(q4 * 4 + r) * (H_ * HD_) + nt2 * 16 + i16] =
                (f16)(o[nt2][r] * inv2[r]);
}

// ---------------------------------------------------------------------------
extern "C" void kernel_launch(void* const* d_in, const int* in_sizes, int n_in,
                              void* d_out, int out_size, void* d_ws, size_t ws_size,
                              hipStream_t stream) {
    const float* x    = (const float*)d_in[0];
    const float* cosb = (const float*)d_in[1];
    const float* sinb = (const float*)d_in[2];
    const float* wq = (const float*)d_in[4];
    const float* wk = (const float*)d_in[5];
    const float* wv = (const float*)d_in[6];
    const float* wo = (const float*)d_in[7];
    const float* qw = (const float*)d_in[8];
    const float* kw = (const float*)d_in[9];
    float* out = (float*)d_out;

    f16* ws = (f16*)d_ws;
    f16* xh    = ws;                       // 8388608 (aliased as attnh later)
    f16* BT    = xh + 8388608;             // 6291456  [3072][2048]
    f16* woT   = BT + 6291456;             // 4194304  [2048][2048]
    f16* QKVh  = woT + 4194304;            // 12582912 [4096][3072]
    f16* Kh    = QKVh + 12582912;          // 2097152
    f16* Vt    = Kh + 2097152;             // 2097152
    f16* attnh = xh;                       // alias: xh dead after QKV GEMM

    const int M = B_ * S_;  // 4096

    // 1) convert x + transpose all weights (one dispatch)
    prep<<<8192 + 2560, 256, 0, stream>>>(x, wq, wk, wv, wo, xh, BT, woT);

    // 2) fused QKV projection: [4096][2048] @ [3072][2048]^T
    //    8-phase 256x256 v2 (fragment reuse + 32x32x16).  grid 12x16.
    gemm_8p<f16><<<dim3(12, 16), 512, 0, stream>>>(xh, BT, QKVh, M, 3072, D_);

    // 3) K norm+rope -> Kh, V norm+transpose -> Vt (Q fused into attn)
    norm_kv_f16<<<NRBK_ + 128, 256, 0, stream>>>(QKVh, Kh, Vt, cosb, sinb, kw);

    // 4) flash attention (fused Q norm+rope, double-buffered staging)
    attn_mfma<<<dim3(S_ / 128, H_, B_), 512, 0, stream>>>(QKVh, Kh, Vt, attnh,
                                                          cosb, sinb, qw);

    // 5) output projection (round-0 proven 2-phase 128x128, fp32 out)
    gemm_f16<float><<<dim3(16, 32), 256, 0, stream>>>(attnh, woT, out, M, D_, H_ * HD_);
}

// Round 4
// 311.787 us; speedup vs baseline: 1.0089x; 1.0089x over previous
//
#include <hip/hip_runtime.h>
#include <hip/hip_bf16.h>
#include <hip/hip_fp16.h>
#include <type_traits>

#define B_ 2
#define S_ 2048
#define D_ 2048
#define H_ 8
#define KV_ 2
#define HD_ 256
#define WINDOW_ 512
#define EPS_ 1e-6f
#define MASKV_ -30000.0f

typedef _Float16 f16;
typedef _Float16 half8 __attribute__((ext_vector_type(8)));
typedef _Float16 half2v __attribute__((ext_vector_type(2)));
typedef _Float16 half4v __attribute__((ext_vector_type(4)));
typedef float floatx4 __attribute__((ext_vector_type(4)));
typedef float floatx8 __attribute__((ext_vector_type(8)));
typedef float floatx16 __attribute__((ext_vector_type(16)));

#define GLOAD_LDS16(g, l)                                                        \
    __builtin_amdgcn_global_load_lds(                                            \
        (const __attribute__((address_space(1))) unsigned int*)(g),              \
        (__attribute__((address_space(3))) unsigned int*)(l), 16, 0, 0)

#define VMWAIT(n) asm volatile("s_waitcnt vmcnt(" #n ")" ::: "memory")
#define LGKM0 asm volatile("s_waitcnt lgkmcnt(0)" ::: "memory")

// ---------------------------------------------------------------------------
// prep: fp32->fp16 convert of x + all 4 weight transposes.  (round-0, proven)
// ---------------------------------------------------------------------------
__global__ __launch_bounds__(256) void prep(const float* __restrict__ x,
                                            const float* __restrict__ wq,
                                            const float* __restrict__ wk,
                                            const float* __restrict__ wv,
                                            const float* __restrict__ wo,
                                            f16* __restrict__ xh,
                                            f16* __restrict__ BT,
                                            f16* __restrict__ woT) {
    int bid = blockIdx.x;
    const int t = threadIdx.x;
    if (bid < 8192) {
        const int i = bid * 256 + t;
        float4 v = ((const float4*)x)[i];
        half4v hv = {(f16)v.x, (f16)v.y, (f16)v.z, (f16)v.w};
        ((half4v*)xh)[i] = hv;
        return;
    }
    bid -= 8192;
    const float* src;
    f16* dst;
    int C, bx, by;
    if (bid < 1024) {
        src = wq; dst = BT; C = 2048; bx = bid & 31; by = bid >> 5;
    } else if (bid < 1280) {
        const int b3 = bid - 1024;
        src = wk; dst = BT + (size_t)2048 * 2048; C = 512; bx = b3 & 7; by = b3 >> 3;
    } else if (bid < 1536) {
        const int b3 = bid - 1280;
        src = wv; dst = BT + (size_t)2560 * 2048; C = 512; bx = b3 & 7; by = b3 >> 3;
    } else {
        const int b3 = bid - 1536;
        src = wo; dst = woT; C = 2048; bx = b3 & 31; by = b3 >> 5;
    }
    __shared__ float tl[64][65];
    const int c0 = bx * 64, r0 = by * 64;
#pragma unroll
    for (int i = 0; i < 4; ++i) {
        const int idx = i * 256 + t;
        const int row = idx >> 4;
        const int c4 = (idx & 15) * 4;
        float4 v = *(const float4*)&src[(size_t)(r0 + row) * C + c0 + c4];
        tl[row][c4 + 0] = v.x; tl[row][c4 + 1] = v.y;
        tl[row][c4 + 2] = v.z; tl[row][c4 + 3] = v.w;
    }
    __syncthreads();
#pragma unroll
    for (int i = 0; i < 4; ++i) {
        const int idx = i * 256 + t;
        const int c = idx >> 4;
        const int r4 = (idx & 15) * 4;
        half4v hv = {(f16)tl[r4 + 0][c], (f16)tl[r4 + 1][c],
                     (f16)tl[r4 + 2][c], (f16)tl[r4 + 3][c]};
        *(half4v*)&dst[(size_t)(c0 + c) * 2048 + r0 + r4] = hv;
    }
}

// ---------------------------------------------------------------------------
// 2-phase fp16 MFMA GEMM (round-0, proven) — used for out-projection.
// ---------------------------------------------------------------------------
#define CH_ 528  // chunk stride in f16
template <typename OutT>
__global__ __launch_bounds__(256) void gemm_f16(const f16* __restrict__ A,
                                                const f16* __restrict__ BT,
                                                OutT* __restrict__ C,
                                                int M, int N, int K) {
    __shared__ __align__(16) f16 sA[16 * CH_];
    __shared__ __align__(16) f16 sB[16 * CH_];

    const int t = threadIdx.x;
    const int lane = t & 63;
    const int w = t >> 6;
    const int l31 = lane & 31, q1 = lane >> 5;
    const int m0 = blockIdx.y * 128, n0 = blockIdx.x * 128;
    const int mw = (w & 1) * 64, nw = (w >> 1) * 64;

    floatx16 acc[4];
#pragma unroll
    for (int i = 0; i < 4; ++i) acc[i] = (floatx16)(0.f);

    const int r8 = lane >> 3;
    const int g = (lane & 7) ^ r8;

    for (int k0 = 0; k0 < K; k0 += 64) {
#pragma unroll
        for (int cc = 0; cc < 4; ++cc) {
            const int chunk = w * 4 + cc;
            const int row = chunk * 8 + r8;
            GLOAD_LDS16(A + (size_t)(m0 + row) * K + k0 + g * 8,
                        sA + chunk * CH_ + lane * 8);
            GLOAD_LDS16(BT + (size_t)(n0 + row) * K + k0 + g * 8,
                        sB + chunk * CH_ + lane * 8);
        }
        __syncthreads();

#pragma unroll
        for (int ks = 0; ks < 4; ++ks) {
            const int G = ks * 2 + q1;
            half8 af[2], bf[2];
#pragma unroll
            for (int mt = 0; mt < 2; ++mt) {
                const int ra = mw + mt * 32 + l31;
                af[mt] = *(const half8*)(sA + (ra >> 3) * CH_ + (ra & 7) * 64 +
                                         (G ^ (ra & 7)) * 8);
                const int rb = nw + mt * 32 + l31;
                bf[mt] = *(const half8*)(sB + (rb >> 3) * CH_ + (rb & 7) * 64 +
                                         (G ^ (rb & 7)) * 8);
            }
#pragma unroll
            for (int mt = 0; mt < 2; ++mt)
#pragma unroll
                for (int nt = 0; nt < 2; ++nt)
                    acc[mt * 2 + nt] = __builtin_amdgcn_mfma_f32_32x32x16_f16(
                        af[mt], bf[nt], acc[mt * 2 + nt], 0, 0, 0);
        }
        __syncthreads();
    }

#pragma unroll
    for (int mt = 0; mt < 2; ++mt)
#pragma unroll
        for (int nt = 0; nt < 2; ++nt)
#pragma unroll
            for (int r = 0; r < 16; ++r) {
                const int row = m0 + mw + mt * 32 + (r & 3) + 8 * (r >> 2) + 4 * q1;
                const int col = n0 + nw + nt * 32 + l31;
                C[(size_t)row * N + col] = (OutT)acc[mt * 2 + nt][r];
            }
}

// ---------------------------------------------------------------------------
// 8-phase 256x256 MFMA GEMM, v3: m201 lockstep schedule + fragment reuse +
// 16x16x32 MFMA (v1's measured-0-conflict LDS addressing).
//
// Per phase (m201 skeleton):
//   { ds_read frags ; stage 1 half-tile ; s_barrier ; lgkmcnt(0) ;
//     setprio(1) ; 16x MFMA ; setprio(0) ; [vmcnt(N)] ; s_barrier }
// The vmcnt before the TRAILING barrier guards the NEXT phase's ds_reads
// (every wave's vmcnt precedes the barrier the readers cross -> cross-wave
// DMA visibility is sound).
//
// Quadrant order per tile: (0,0)->(0,1)->(1,1)->(1,0); reads per phase
// 12/4/8/4 (a-half and b-half fragments held across phases).  Staging
// issue order = first-use order A0,B0,B1,A1, one half-tile (2 loads) per
// phase, 4-slot ring per operand (slot=(2T+half)&3) -> T+1's stagings
// never touch slots tile T reads.
//
// vmcnt ledger (in loads, 2/staging), steady state:
//   end ph0: queue [B1(T),A1(T),A0'] guard B1 -> vmcnt(4)
//   end ph1: queue [A1(T),A0',B0']   guard A1 -> vmcnt(4)
//   end ph2: ph3 reads old b0        -> no wait
//   end ph3: queue [A0',B0',B1',A1'] guard A0',B0' -> vmcnt(4)
// Tail (no staging): end ph0 -> vmcnt(2), end ph1 -> vmcnt(0).
// >=4 loads in flight at every steady-state wait (T4: never drain).
//
// LDS swizzle (measured 0 conflicts, r2): 16B-slot q of row r holds global
// k-group q^(r&7) (pre-swizzled GLOBAL source, linear global_load_lds dst);
// read k-group G=ks*4+q4 at row r -> slot G^(r&7).
// Frag (16x16x32): rows i16, k=(q4*8+j).  C/D: row=q4*4+reg, col=i16
// (round-0/r2-verified epilogue).
// ---------------------------------------------------------------------------
template <typename OutT>
__global__ __launch_bounds__(512, 2) void gemm_8p(const f16* __restrict__ A,
                                                  const f16* __restrict__ BT,
                                                  OutT* __restrict__ C,
                                                  int M, int N, int K) {
    __shared__ __align__(16) f16 sAA[4 * 8192];  // 64 KB: 4 half-slots, 128x64
    __shared__ __align__(16) f16 sBB[4 * 8192];  // 64 KB

    const int tid = threadIdx.x;
    const int lane = tid & 63, w = tid >> 6;
    const int i16 = lane & 15, q4 = lane >> 4;
    const int w1 = w & 1, w2 = w >> 1;
    const int m0 = blockIdx.y * 256, n0 = blockIdx.x * 256;

    // staging: thread covers LDS bytes tid*16 and tid*16+8192 of a half.
    const int kx = ((tid & 7) ^ ((tid >> 3) & 7)) * 8;   // pre-swizzled src k
    const f16* srcA0 = A + (size_t)(m0 + (tid >> 3)) * K;
    const f16* srcB0 = BT + (size_t)(n0 + (tid >> 3)) * K;
    f16* dstA0 = sAA + tid * 8;
    f16* dstB0 = sBB + tid * 8;

    auto stageA = [&](int half, int kt) {
        const int slot = (2 * kt + half) & 3;
        const f16* s = srcA0 + (size_t)(half * 128) * K + kt * 64 + kx;
        f16* d = dstA0 + slot * 8192;
        GLOAD_LDS16(s, d);
        GLOAD_LDS16(s + (size_t)64 * K, d + 4096);
    };
    auto stageB = [&](int half, int kt) {
        const int slot = (2 * kt + half) & 3;
        const f16* s = srcB0 + (size_t)(half * 128) * K + kt * 64 + kx;
        f16* d = dstB0 + slot * 8192;
        GLOAD_LDS16(s, d);
        GLOAD_LDS16(s + (size_t)64 * K, d + 4096);
    };

    // fragment-read offsets (f16 units), v1-exact (0 conflicts measured)
    const int arow = (w1 * 64 + i16) * 64;   // + mt*1024
    const int brow = (w2 * 32 + i16) * 64;   // + nt*1024
    int xk[2];
    xk[0] = ((0 + q4) ^ (i16 & 7)) * 8;
    xk[1] = ((4 + q4) ^ (i16 & 7)) * 8;

    // acc[p][mt][nt]: p = quadrant in order (0,0),(0,1),(1,1),(1,0)
    floatx4 acc[4][4][2];
#pragma unroll
    for (int p = 0; p < 4; ++p)
#pragma unroll
        for (int mt = 0; mt < 4; ++mt)
#pragma unroll
            for (int nt = 0; nt < 2; ++nt)
                acc[p][mt][nt] = (floatx4){0.f, 0.f, 0.f, 0.f};

    int st = 0;  // tile T's slot base (0 or 2); half h of T at slot st+h

    const int NT = K >> 6;  // K / 64

    // prologue: tile 0's stagings in first-use order; guard A0,B0
    stageA(0, 0); stageB(0, 0); stageB(1, 0); stageA(1, 0);
    VMWAIT(4);
    __builtin_amdgcn_s_barrier();

    half8 af[4][2], bf[2][2];

#define READ_A(ptr)                                                           \
    _Pragma("unroll") for (int mt = 0; mt < 4; ++mt)                          \
        _Pragma("unroll") for (int ks = 0; ks < 2; ++ks)                      \
            af[mt][ks] = *(const half8*)((ptr) + arow + mt * 1024 + xk[ks]);
#define READ_B(ptr)                                                           \
    _Pragma("unroll") for (int nt = 0; nt < 2; ++nt)                          \
        _Pragma("unroll") for (int ks = 0; ks < 2; ++ks)                      \
            bf[nt][ks] = *(const half8*)((ptr) + brow + nt * 1024 + xk[ks]);
#define DO_MFMA(p)                                                            \
    __builtin_amdgcn_s_setprio(1);                                            \
    _Pragma("unroll") for (int mt = 0; mt < 4; ++mt)                          \
        _Pragma("unroll") for (int nt = 0; nt < 2; ++nt)                      \
            _Pragma("unroll") for (int ks = 0; ks < 2; ++ks)                  \
                acc[p][mt][nt] = __builtin_amdgcn_mfma_f32_16x16x32_f16(      \
                    af[mt][ks], bf[nt][ks], acc[p][mt][nt], 0, 0, 0);         \
    __builtin_amdgcn_s_setprio(0);

    auto tile = [&](auto LASTC, int T) {
        constexpr bool LAST = decltype(LASTC)::value;
        const f16* a0p = sAA + (size_t)(st + 0) * 8192;
        const f16* a1p = sAA + (size_t)(st + 1) * 8192;
        const f16* b0p = sBB + (size_t)(st + 0) * 8192;
        const f16* b1p = sBB + (size_t)(st + 1) * 8192;

        // ---- ph0: q(0,0) = a0 x b0 ----
        READ_A(a0p); READ_B(b0p);
        if constexpr (!LAST) stageA(0, T + 1);
        __builtin_amdgcn_s_barrier();
        LGKM0;
        DO_MFMA(0);
        if constexpr (!LAST) VMWAIT(4); else VMWAIT(2);
        __builtin_amdgcn_s_barrier();

        // ---- ph1: q(0,1) = a0 x b1  (af held) ----
        READ_B(b1p);
        if constexpr (!LAST) stageB(0, T + 1);
        __builtin_amdgcn_s_barrier();
        LGKM0;
        DO_MFMA(1);
        if constexpr (!LAST) VMWAIT(4); else VMWAIT(0);
        __builtin_amdgcn_s_barrier();

        // ---- ph2: q(1,1) = a1 x b1  (bf held) ----
        READ_A(a1p);
        if constexpr (!LAST) stageB(1, T + 1);
        __builtin_amdgcn_s_barrier();
        LGKM0;
        DO_MFMA(2);
        __builtin_amdgcn_s_barrier();

        // ---- ph3: q(1,0) = a1 x b0  (af held) ----
        READ_B(b0p);
        if constexpr (!LAST) stageA(1, T + 1);
        __builtin_amdgcn_s_barrier();
        LGKM0;
        DO_MFMA(3);
        if constexpr (!LAST) { VMWAIT(4); }
        __builtin_amdgcn_s_barrier();
    };

    for (int T = 0; T < NT - 1; ++T) {
        tile(std::false_type{}, T);
        st ^= 2;
    }
    tile(std::true_type{}, NT - 1);

#undef READ_A
#undef READ_B
#undef DO_MFMA

    // epilogue: quadrant p -> (qm,qn); 16x16 C/D: row=q4*4+reg, col=i16
    const int qmv[4] = {0, 0, 1, 1};
    const int qnv[4] = {0, 1, 1, 0};
#pragma unroll
    for (int p = 0; p < 4; ++p) {
        const int rb = m0 + qmv[p] * 128 + w1 * 64 + q4 * 4;
        const int cb = n0 + qnv[p] * 128 + w2 * 32 + i16;
#pragma unroll
        for (int mt = 0; mt < 4; ++mt)
#pragma unroll
            for (int nt = 0; nt < 2; ++nt) {
                floatx4 v = acc[p][mt][nt];
#pragma unroll
                for (int r = 0; r < 4; ++r)
                    C[(size_t)(rb + mt * 16 + r) * N + cb + nt * 16] = (OutT)v[r];
            }
    }
}

// ---------------------------------------------------------------------------
// K/V norm kernel (round-0, proven).
// ---------------------------------------------------------------------------
#define NRBK_ ((B_ * S_ * KV_) / 4)  // 2048 blocks, 4 waves each

__global__ __launch_bounds__(256) void norm_kv_f16(
    const f16* __restrict__ QKVh, f16* __restrict__ Kh, f16* __restrict__ Vt,
    const float* __restrict__ cosb, const float* __restrict__ sinb,
    const float* __restrict__ kw) {
    __shared__ f16 vt[64][266];

    const int w = threadIdx.x >> 6, lane = threadIdx.x & 63;

    if (blockIdx.x < NRBK_) {
        const int wid = blockIdx.x * 4 + w;
        const int d0 = lane * 2;
        const int b = wid / (S_ * KV_);
        const int r = wid % (S_ * KV_);
        const int s = r / KV_, kv = r % KV_;
        const f16* p = QKVh + (size_t)(b * S_ + s) * 3072 + 2048 + kv * HD_;
        half2v lo = *(const half2v*)(p + d0);
        half2v hi = *(const half2v*)(p + 128 + d0);
        float x0 = (float)lo[0], x1 = (float)lo[1], x2 = (float)hi[0], x3 = (float)hi[1];
        float ss = x0 * x0 + x1 * x1 + x2 * x2 + x3 * x3;
#pragma unroll
        for (int off = 32; off >= 1; off >>= 1) ss += __shfl_xor(ss, off);
        const float inv = rsqrtf(ss * (1.0f / HD_) + EPS_);
        float2 wlo = *(const float2*)(kw + d0), whi = *(const float2*)(kw + 128 + d0);
        float y0 = x0 * inv * wlo.x, y1 = x1 * inv * wlo.y;
        float y2 = x2 * inv * whi.x, y3 = x3 * inv * whi.y;
        const float* cb = cosb + (size_t)(b * S_ + s) * HD_;
        const float* sb = sinb + (size_t)(b * S_ + s) * HD_;
        float2 clo = *(const float2*)(cb + d0), chi = *(const float2*)(cb + 128 + d0);
        float2 slo = *(const float2*)(sb + d0), shi = *(const float2*)(sb + 128 + d0);
        half2v olo = {(f16)(y0 * clo.x - y2 * slo.x), (f16)(y1 * clo.y - y3 * slo.y)};
        half2v ohi = {(f16)(y2 * chi.x + y0 * shi.x), (f16)(y3 * chi.y + y1 * shi.y)};
        f16* d = Kh + ((size_t)(b * KV_ + kv) * S_ + s) * HD_;
        *(half2v*)(d + d0) = olo;
        *(half2v*)(d + 128 + d0) = ohi;
        return;
    }

    const int vb = blockIdx.x - NRBK_;
    const int s0 = (vb & 31) * 64;
    const int kv = (vb >> 5) & 1;
    const int b  = vb >> 6;

    for (int r = 0; r < 16; ++r) {
        const int sl = w * 16 + r;
        const f16* p = QKVh + (size_t)(b * S_ + s0 + sl) * 3072 + 2560 + kv * HD_;
        const int d0 = lane * 2;
        half2v lo = *(const half2v*)(p + d0);
        half2v hi = *(const half2v*)(p + 128 + d0);
        float x0 = (float)lo[0], x1 = (float)lo[1], x2 = (float)hi[0], x3 = (float)hi[1];
        float ss = x0 * x0 + x1 * x1 + x2 * x2 + x3 * x3;
#pragma unroll
        for (int off = 32; off >= 1; off >>= 1) ss += __shfl_xor(ss, off);
        const float inv = rsqrtf(ss * (1.0f / HD_) + EPS_);
        half2v olo = {(f16)(x0 * inv), (f16)(x1 * inv)};
        half2v ohi = {(f16)(x2 * inv), (f16)(x3 * inv)};
        *(half2v*)&vt[sl][d0] = olo;
        *(half2v*)&vt[sl][128 + d0] = ohi;
    }
    __syncthreads();
    f16* dst = Vt + (size_t)(b * KV_ + kv) * HD_ * S_;
    for (int i = 0; i < 64; ++i) {
        const int dd = w * 64 + i;
        dst[(size_t)dd * S_ + s0 + lane] = vt[lane][dd];
    }
}

// ---------------------------------------------------------------------------
// MFMA flash attention (round-0, proven). 128 q, 8 waves, dbuf staging.
// ---------------------------------------------------------------------------
__global__ __launch_bounds__(512, 2) void attn_mfma(const f16* __restrict__ QKVh,
                                                    const f16* __restrict__ Kh,
                                                    const f16* __restrict__ Vt,
                                                    f16* __restrict__ attnh,
                                                    const float* __restrict__ cosb,
                                                    const float* __restrict__ sinb,
                                                    const float* __restrict__ qw) {
    __shared__ __align__(16) f16 sK[2][64 * 256];
    __shared__ __align__(16) f16 sV[2][256 * 64];
    __shared__ __align__(16) f16 sP[8][16 * 72];

    const int qt = blockIdx.x, h = blockIdx.y, b = blockIdx.z;
    const int kvh = h / (H_ / KV_);
    const int t = threadIdx.x, lane = t & 63, w = t >> 6;
    const int i16 = lane & 15, q4 = lane >> 4;

    const int qrow = qt * 128 + w * 16 + i16;
    const f16* qbase = QKVh + (size_t)(b * S_ + qrow) * 3072 + h * HD_ + q4 * 8;
    half8 qf[8];
#pragma unroll
    for (int kk = 0; kk < 8; ++kk) qf[kk] = *(const half8*)(qbase + kk * 32);

    {
        float ss = 0.f;
#pragma unroll
        for (int kk = 0; kk < 8; ++kk)
#pragma unroll
            for (int j = 0; j < 8; ++j) {
                const float v = (float)qf[kk][j];
                ss += v * v;
            }
        ss += __shfl_xor(ss, 16);
        ss += __shfl_xor(ss, 32);
        const float inv = rsqrtf(ss * (1.0f / HD_) + EPS_);
        const float* cb = cosb + (size_t)(b * S_ + qrow) * HD_ + q4 * 8;
        const float* sb = sinb + (size_t)(b * S_ + qrow) * HD_ + q4 * 8;
        const float* wp = qw + q4 * 8;
#pragma unroll
        for (int kk = 0; kk < 4; ++kk) {
            const int dl = kk * 32, dh = dl + 128;
            floatx8 cl = *(const floatx8*)(cb + dl);
            floatx8 ch = *(const floatx8*)(cb + dh);
            floatx8 sl = *(const floatx8*)(sb + dl);
            floatx8 sh = *(const floatx8*)(sb + dh);
            floatx8 wl = *(const floatx8*)(wp + dl);
            floatx8 wh = *(const floatx8*)(wp + dh);
            half8 nl, nh;
#pragma unroll
            for (int j = 0; j < 8; ++j) {
                const float xl = (float)qf[kk][j] * inv * wl[j];
                const float xh = (float)qf[kk + 4][j] * inv * wh[j];
                nl[j] = (f16)(xl * cl[j] - xh * sl[j]);
                nh[j] = (f16)(xh * ch[j] + xl * sh[j]);
            }
            qf[kk] = nl;
            qf[kk + 4] = nh;
        }
    }

    floatx4 o[16];
#pragma unroll
    for (int i = 0; i < 16; ++i) o[i] = (floatx4){0.f, 0.f, 0.f, 0.f};
    float mrow[4] = {-1e30f, -1e30f, -1e30f, -1e30f};
    float lrow[4] = {0.f, 0.f, 0.f, 0.f};

    const size_t kbase = (size_t)(b * KV_ + kvh) * S_ * HD_;
    const size_t vbase = (size_t)(b * KV_ + kvh) * HD_ * S_;
    const int srow0 = qt * 128 + w * 16 + q4 * 4;

    const int kt_lo = (2 * qt - 8) > 0 ? (2 * qt - 8) : 0;
    const int kt_hi = 2 * qt + 1;
    const int s_lo_w = qt * 128 + w * 16;
    int ktw_lo = (s_lo_w - (WINDOW_ - 1)) >> 6;
    if (ktw_lo < kt_lo) ktw_lo = kt_lo;
    const int ktw_hi = (s_lo_w + 15) >> 6;

    auto stage = [&](int kt, int buf) {
#pragma unroll
        for (int c = 0; c < 4; ++c) {
            const int chunk = w * 4 + c;
            const int keyl = chunk * 2 + (lane >> 5);
            const int g = (lane & 31) ^ (keyl & 31);
            GLOAD_LDS16(Kh + kbase + (size_t)(kt * 64 + keyl) * HD_ + g * 8,
                        sK[buf] + chunk * 512 + lane * 8);
            const int diml = chunk * 8 + (lane >> 3);
            const int g2 = (lane & 7) ^ (diml & 7);
            GLOAD_LDS16(Vt + vbase + (size_t)diml * S_ + kt * 64 + g2 * 8,
                        sV[buf] + chunk * 512 + lane * 8);
        }
    };

    stage(kt_lo, 0);
    int cur = 0;
    for (int kt = kt_lo; kt <= kt_hi; ++kt, cur ^= 1) {
        __syncthreads();
        if (kt < kt_hi) stage(kt + 1, cur ^ 1);
        if (kt < ktw_lo || kt > ktw_hi) continue;

        const f16* sKc = sK[cur];
        const f16* sVc = sV[cur];

        floatx4 sc[4];
#pragma unroll
        for (int nt = 0; nt < 4; ++nt) sc[nt] = (floatx4){0.f, 0.f, 0.f, 0.f};
#pragma unroll
        for (int ks = 0; ks < 8; ++ks)
#pragma unroll
            for (int nt = 0; nt < 4; ++nt) {
                const int keyl = nt * 16 + i16;
                const int gp = (ks * 4 + q4) ^ (keyl & 31);
                half8 kf = *(const half8*)(sKc + keyl * 256 + gp * 8);
                sc[nt] = __builtin_amdgcn_mfma_f32_16x16x32_f16(qf[ks], kf, sc[nt], 0, 0, 0);
            }

#pragma unroll
        for (int r = 0; r < 4; ++r) {
            const int s = srow0 + r;
            float mx = -1e30f;
#pragma unroll
            for (int nt = 0; nt < 4; ++nt) {
                const int j = kt * 64 + nt * 16 + i16;
                const bool valid = (j <= s) && (s - j < WINDOW_);
                const float v = valid ? sc[nt][r] : MASKV_;
                sc[nt][r] = v;
                mx = fmaxf(mx, v);
            }
#pragma unroll
            for (int off = 1; off < 16; off <<= 1) mx = fmaxf(mx, __shfl_xor(mx, off));
            const float mnew = fmaxf(mrow[r], mx);
            const float alpha = __expf(mrow[r] - mnew);
            mrow[r] = mnew;
            float rs = 0.f;
#pragma unroll
            for (int nt = 0; nt < 4; ++nt) {
                const float p = __expf(sc[nt][r] - mnew);
                sc[nt][r] = p;
                rs += p;
            }
#pragma unroll
            for (int off = 1; off < 16; off <<= 1) rs += __shfl_xor(rs, off);
            lrow[r] = lrow[r] * alpha + rs;
#pragma unroll
            for (int nt2 = 0; nt2 < 16; ++nt2) o[nt2][r] *= alpha;
        }

        f16* sPw = sP[w];
#pragma unroll
        for (int nt = 0; nt < 4; ++nt)
#pragma unroll
            for (int r = 0; r < 4; ++r)
                sPw[(q4 * 4 + r) * 72 + nt * 16 + i16] = (f16)sc[nt][r];
        asm volatile("s_waitcnt lgkmcnt(0)" ::: "memory");

#pragma unroll
        for (int kt2 = 0; kt2 < 2; ++kt2) {
            half8 pf = *(const half8*)(sPw + i16 * 72 + kt2 * 32 + q4 * 8);
#pragma unroll
            for (int nt2 = 0; nt2 < 16; ++nt2) {
                const int dim = nt2 * 16 + i16;
                const int gp = (kt2 * 4 + q4) ^ (dim & 7);
                half8 vf = *(const half8*)(sVc + dim * 64 + gp * 8);
                o[nt2] = __builtin_amdgcn_mfma_f32_16x16x32_f16(pf, vf, o[nt2], 0, 0, 0);
            }
        }
    }

    float inv2[4];
#pragma unroll
    for (int r = 0; r < 4; ++r) inv2[r] = 1.0f / lrow[r];
    f16* ob = attnh + (size_t)(b * S_ + qt * 128 + w * 16) * (H_ * HD_) + h * HD_;
#pragma unroll
    for (int nt2 = 0; nt2 < 16; ++nt2)
#pragma unroll
        for (int r = 0; r < 4; ++r)
            ob[(size_t)(q4 * 4 + r) * (H_ * HD_) + nt2 * 16 + i16] =
                (f16)(o[nt2][r] * inv2[r]);
}

// ---------------------------------------------------------------------------
extern "C" void kernel_launch(void* const* d_in, const int* in_sizes, int n_in,
                              void* d_out, int out_size, void* d_ws, size_t ws_size,
                              hipStream_t stream) {
    const float* x    = (const float*)d_in[0];
    const float* cosb = (const float*)d_in[1];
    const float* sinb = (const float*)d_in[2];
    const float* wq = (const float*)d_in[4];
    const float* wk = (const float*)d_in[5];
    const float* wv = (const float*)d_in[6];
    const float* wo = (const float*)d_in[7];
    const float* qw = (const float*)d_in[8];
    const float* kw = (const float*)d_in[9];
    float* out = (float*)d_out;

    f16* ws = (f16*)d_ws;
    f16* xh    = ws;                       // 8388608 (aliased as attnh later)
    f16* BT    = xh + 8388608;             // 6291456  [3072][2048]
    f16* woT   = BT + 6291456;             // 4194304  [2048][2048]
    f16* QKVh  = woT + 4194304;            // 12582912 [4096][3072]
    f16* Kh    = QKVh + 12582912;          // 2097152
    f16* Vt    = Kh + 2097152;             // 2097152
    f16* attnh = xh;                       // alias: xh dead after QKV GEMM

    const int M = B_ * S_;  // 4096

    // 1) convert x + transpose all weights (one dispatch)
    prep<<<8192 + 2560, 256, 0, stream>>>(x, wq, wk, wv, wo, xh, BT, woT);

    // 2) fused QKV projection: [4096][2048] @ [3072][2048]^T
    //    8-phase 256x256 v3 (m201 lockstep + reuse + 16x16x32).  grid 12x16.
    gemm_8p<f16><<<dim3(12, 16), 512, 0, stream>>>(xh, BT, QKVh, M, 3072, D_);

    // 3) K norm+rope -> Kh, V norm+transpose -> Vt (Q fused into attn)
    norm_kv_f16<<<NRBK_ + 128, 256, 0, stream>>>(QKVh, Kh, Vt, cosb, sinb, kw);

    // 4) flash attention (fused Q norm+rope, double-buffered staging)
    attn_mfma<<<dim3(S_ / 128, H_, B_), 512, 0, stream>>>(QKVh, Kh, Vt, attnh,
                                                          cosb, sinb, qw);

    // 5) output projection (round-0 proven 2-phase 128x128, fp32 out)
    gemm_f16<float><<<dim3(16, 32), 256, 0, stream>>>(attnh, woT, out, M, D_, H_ * HD_);
}

// Round 5
// 309.877 us; speedup vs baseline: 1.0151x; 1.0062x over previous
//
#include <hip/hip_runtime.h>
#include <hip/hip_bf16.h>
#include <hip/hip_fp16.h>

#define B_ 2
#define S_ 2048
#define D_ 2048
#define H_ 8
#define KV_ 2
#define HD_ 256
#define WINDOW_ 512
#define EPS_ 1e-6f
#define MASKV_ -30000.0f

typedef _Float16 f16;
typedef _Float16 half8 __attribute__((ext_vector_type(8)));
typedef _Float16 half2v __attribute__((ext_vector_type(2)));
typedef _Float16 half4v __attribute__((ext_vector_type(4)));
typedef float floatx4 __attribute__((ext_vector_type(4)));
typedef float floatx8 __attribute__((ext_vector_type(8)));
typedef float floatx16 __attribute__((ext_vector_type(16)));

#define GLOAD_LDS16(g, l)                                                        \
    __builtin_amdgcn_global_load_lds(                                            \
        (const __attribute__((address_space(1))) unsigned int*)(g),              \
        (__attribute__((address_space(3))) unsigned int*)(l), 16, 0, 0)

// ---------------------------------------------------------------------------
// prep: fp32->fp16 convert of x + all 4 weight transposes.  (round-0, proven)
// ---------------------------------------------------------------------------
__global__ __launch_bounds__(256) void prep(const float* __restrict__ x,
                                            const float* __restrict__ wq,
                                            const float* __restrict__ wk,
                                            const float* __restrict__ wv,
                                            const float* __restrict__ wo,
                                            f16* __restrict__ xh,
                                            f16* __restrict__ BT,
                                            f16* __restrict__ woT) {
    int bid = blockIdx.x;
    const int t = threadIdx.x;
    if (bid < 8192) {
        const int i = bid * 256 + t;
        float4 v = ((const float4*)x)[i];
        half4v hv = {(f16)v.x, (f16)v.y, (f16)v.z, (f16)v.w};
        ((half4v*)xh)[i] = hv;
        return;
    }
    bid -= 8192;
    const float* src;
    f16* dst;
    int C, bx, by;
    if (bid < 1024) {
        src = wq; dst = BT; C = 2048; bx = bid & 31; by = bid >> 5;
    } else if (bid < 1280) {
        const int b3 = bid - 1024;
        src = wk; dst = BT + (size_t)2048 * 2048; C = 512; bx = b3 & 7; by = b3 >> 3;
    } else if (bid < 1536) {
        const int b3 = bid - 1280;
        src = wv; dst = BT + (size_t)2560 * 2048; C = 512; bx = b3 & 7; by = b3 >> 3;
    } else {
        const int b3 = bid - 1536;
        src = wo; dst = woT; C = 2048; bx = b3 & 31; by = b3 >> 5;
    }
    __shared__ float tl[64][65];
    const int c0 = bx * 64, r0 = by * 64;
#pragma unroll
    for (int i = 0; i < 4; ++i) {
        const int idx = i * 256 + t;
        const int row = idx >> 4;
        const int c4 = (idx & 15) * 4;
        float4 v = *(const float4*)&src[(size_t)(r0 + row) * C + c0 + c4];
        tl[row][c4 + 0] = v.x; tl[row][c4 + 1] = v.y;
        tl[row][c4 + 2] = v.z; tl[row][c4 + 3] = v.w;
    }
    __syncthreads();
#pragma unroll
    for (int i = 0; i < 4; ++i) {
        const int idx = i * 256 + t;
        const int c = idx >> 4;
        const int r4 = (idx & 15) * 4;
        half4v hv = {(f16)tl[r4 + 0][c], (f16)tl[r4 + 1][c],
                     (f16)tl[r4 + 2][c], (f16)tl[r4 + 3][c]};
        *(half4v*)&dst[(size_t)(c0 + c) * 2048 + r0 + r4] = hv;
    }
}

// ---------------------------------------------------------------------------
// 2-phase fp16 MFMA GEMM (round-0 structure, proven 65.5 us on QKV) with
// T1 chunked-XCD swizzle: 1-D grid, nwg % 8 == 0 (bijective), XCD k gets the
// contiguous tile range [k*nwg/8, (k+1)*nwg/8) -> its 4 M-panels (2 MB of A)
// stay hot in the XCD's private 4 MB L2 instead of being refetched by blocks
// scattered across all 8 XCDs.  (FETCH_SIZE was 2.5x the unique bytes.)
// ---------------------------------------------------------------------------
#define CH_ 528  // chunk stride in f16
template <typename OutT>
__global__ __launch_bounds__(256) void gemm_f16(const f16* __restrict__ A,
                                                const f16* __restrict__ BT,
                                                OutT* __restrict__ C,
                                                int M, int N, int K, int nbx) {
    __shared__ __align__(16) f16 sA[16 * CH_];
    __shared__ __align__(16) f16 sB[16 * CH_];

    const int t = threadIdx.x;
    const int lane = t & 63;
    const int w = t >> 6;
    const int l31 = lane & 31, q1 = lane >> 5;

    // XCD-chunked bijective remap (nwg multiple of 8)
    const int chunkw = gridDim.x >> 3;
    int bid = blockIdx.x;
    bid = (bid & 7) * chunkw + (bid >> 3);
    const int m0 = (bid / nbx) * 128, n0 = (bid % nbx) * 128;

    const int mw = (w & 1) * 64, nw = (w >> 1) * 64;

    floatx16 acc[4];
#pragma unroll
    for (int i = 0; i < 4; ++i) acc[i] = (floatx16)(0.f);

    const int r8 = lane >> 3;
    const int g = (lane & 7) ^ r8;

    for (int k0 = 0; k0 < K; k0 += 64) {
#pragma unroll
        for (int cc = 0; cc < 4; ++cc) {
            const int chunk = w * 4 + cc;
            const int row = chunk * 8 + r8;
            GLOAD_LDS16(A + (size_t)(m0 + row) * K + k0 + g * 8,
                        sA + chunk * CH_ + lane * 8);
            GLOAD_LDS16(BT + (size_t)(n0 + row) * K + k0 + g * 8,
                        sB + chunk * CH_ + lane * 8);
        }
        __syncthreads();

#pragma unroll
        for (int ks = 0; ks < 4; ++ks) {
            const int G = ks * 2 + q1;
            half8 af[2], bf[2];
#pragma unroll
            for (int mt = 0; mt < 2; ++mt) {
                const int ra = mw + mt * 32 + l31;
                af[mt] = *(const half8*)(sA + (ra >> 3) * CH_ + (ra & 7) * 64 +
                                         (G ^ (ra & 7)) * 8);
                const int rb = nw + mt * 32 + l31;
                bf[mt] = *(const half8*)(sB + (rb >> 3) * CH_ + (rb & 7) * 64 +
                                         (G ^ (rb & 7)) * 8);
            }
#pragma unroll
            for (int mt = 0; mt < 2; ++mt)
#pragma unroll
                for (int nt = 0; nt < 2; ++nt)
                    acc[mt * 2 + nt] = __builtin_amdgcn_mfma_f32_32x32x16_f16(
                        af[mt], bf[nt], acc[mt * 2 + nt], 0, 0, 0);
        }
        __syncthreads();
    }

#pragma unroll
    for (int mt = 0; mt < 2; ++mt)
#pragma unroll
        for (int nt = 0; nt < 2; ++nt)
#pragma unroll
            for (int r = 0; r < 16; ++r) {
                const int row = m0 + mw + mt * 32 + (r & 3) + 8 * (r >> 2) + 4 * q1;
                const int col = n0 + nw + nt * 32 + l31;
                C[(size_t)row * N + col] = (OutT)acc[mt * 2 + nt][r];
            }
}

// ---------------------------------------------------------------------------
// K/V norm kernel (round-0, proven).
// ---------------------------------------------------------------------------
#define NRBK_ ((B_ * S_ * KV_) / 4)  // 2048 blocks, 4 waves each

__global__ __launch_bounds__(256) void norm_kv_f16(
    const f16* __restrict__ QKVh, f16* __restrict__ Kh, f16* __restrict__ Vt,
    const float* __restrict__ cosb, const float* __restrict__ sinb,
    const float* __restrict__ kw) {
    __shared__ f16 vt[64][266];

    const int w = threadIdx.x >> 6, lane = threadIdx.x & 63;

    if (blockIdx.x < NRBK_) {
        const int wid = blockIdx.x * 4 + w;
        const int d0 = lane * 2;
        const int b = wid / (S_ * KV_);
        const int r = wid % (S_ * KV_);
        const int s = r / KV_, kv = r % KV_;
        const f16* p = QKVh + (size_t)(b * S_ + s) * 3072 + 2048 + kv * HD_;
        half2v lo = *(const half2v*)(p + d0);
        half2v hi = *(const half2v*)(p + 128 + d0);
        float x0 = (float)lo[0], x1 = (float)lo[1], x2 = (float)hi[0], x3 = (float)hi[1];
        float ss = x0 * x0 + x1 * x1 + x2 * x2 + x3 * x3;
#pragma unroll
        for (int off = 32; off >= 1; off >>= 1) ss += __shfl_xor(ss, off);
        const float inv = rsqrtf(ss * (1.0f / HD_) + EPS_);
        float2 wlo = *(const float2*)(kw + d0), whi = *(const float2*)(kw + 128 + d0);
        float y0 = x0 * inv * wlo.x, y1 = x1 * inv * wlo.y;
        float y2 = x2 * inv * whi.x, y3 = x3 * inv * whi.y;
        const float* cb = cosb + (size_t)(b * S_ + s) * HD_;
        const float* sb = sinb + (size_t)(b * S_ + s) * HD_;
        float2 clo = *(const float2*)(cb + d0), chi = *(const float2*)(cb + 128 + d0);
        float2 slo = *(const float2*)(sb + d0), shi = *(const float2*)(sb + 128 + d0);
        half2v olo = {(f16)(y0 * clo.x - y2 * slo.x), (f16)(y1 * clo.y - y3 * slo.y)};
        half2v ohi = {(f16)(y2 * chi.x + y0 * shi.x), (f16)(y3 * chi.y + y1 * shi.y)};
        f16* d = Kh + ((size_t)(b * KV_ + kv) * S_ + s) * HD_;
        *(half2v*)(d + d0) = olo;
        *(half2v*)(d + 128 + d0) = ohi;
        return;
    }

    const int vb = blockIdx.x - NRBK_;
    const int s0 = (vb & 31) * 64;
    const int kv = (vb >> 5) & 1;
    const int b  = vb >> 6;

    for (int r = 0; r < 16; ++r) {
        const int sl = w * 16 + r;
        const f16* p = QKVh + (size_t)(b * S_ + s0 + sl) * 3072 + 2560 + kv * HD_;
        const int d0 = lane * 2;
        half2v lo = *(const half2v*)(p + d0);
        half2v hi = *(const half2v*)(p + 128 + d0);
        float x0 = (float)lo[0], x1 = (float)lo[1], x2 = (float)hi[0], x3 = (float)hi[1];
        float ss = x0 * x0 + x1 * x1 + x2 * x2 + x3 * x3;
#pragma unroll
        for (int off = 32; off >= 1; off >>= 1) ss += __shfl_xor(ss, off);
        const float inv = rsqrtf(ss * (1.0f / HD_) + EPS_);
        half2v olo = {(f16)(x0 * inv), (f16)(x1 * inv)};
        half2v ohi = {(f16)(x2 * inv), (f16)(x3 * inv)};
        *(half2v*)&vt[sl][d0] = olo;
        *(half2v*)&vt[sl][128 + d0] = ohi;
    }
    __syncthreads();
    f16* dst = Vt + (size_t)(b * KV_ + kv) * HD_ * S_;
    for (int i = 0; i < 64; ++i) {
        const int dd = w * 64 + i;
        dst[(size_t)dd * S_ + s0 + lane] = vt[lane][dd];
    }
}

// ---------------------------------------------------------------------------
// MFMA flash attention (round-0 structure) + exact defer-rescale: skip the
// alpha path entirely when the tile brings no new row-max (alpha would be
// exp(0)=1 -> bit-identical result, saves 64 o-mults + exp per skipped row).
// ---------------------------------------------------------------------------
__global__ __launch_bounds__(512, 2) void attn_mfma(const f16* __restrict__ QKVh,
                                                    const f16* __restrict__ Kh,
                                                    const f16* __restrict__ Vt,
                                                    f16* __restrict__ attnh,
                                                    const float* __restrict__ cosb,
                                                    const float* __restrict__ sinb,
                                                    const float* __restrict__ qw) {
    __shared__ __align__(16) f16 sK[2][64 * 256];
    __shared__ __align__(16) f16 sV[2][256 * 64];
    __shared__ __align__(16) f16 sP[8][16 * 72];

    const int qt = blockIdx.x, h = blockIdx.y, b = blockIdx.z;
    const int kvh = h / (H_ / KV_);
    const int t = threadIdx.x, lane = t & 63, w = t >> 6;
    const int i16 = lane & 15, q4 = lane >> 4;

    const int qrow = qt * 128 + w * 16 + i16;
    const f16* qbase = QKVh + (size_t)(b * S_ + qrow) * 3072 + h * HD_ + q4 * 8;
    half8 qf[8];
#pragma unroll
    for (int kk = 0; kk < 8; ++kk) qf[kk] = *(const half8*)(qbase + kk * 32);

    {
        float ss = 0.f;
#pragma unroll
        for (int kk = 0; kk < 8; ++kk)
#pragma unroll
            for (int j = 0; j < 8; ++j) {
                const float v = (float)qf[kk][j];
                ss += v * v;
            }
        ss += __shfl_xor(ss, 16);
        ss += __shfl_xor(ss, 32);
        const float inv = rsqrtf(ss * (1.0f / HD_) + EPS_);
        const float* cb = cosb + (size_t)(b * S_ + qrow) * HD_ + q4 * 8;
        const float* sb = sinb + (size_t)(b * S_ + qrow) * HD_ + q4 * 8;
        const float* wp = qw + q4 * 8;
#pragma unroll
        for (int kk = 0; kk < 4; ++kk) {
            const int dl = kk * 32, dh = dl + 128;
            floatx8 cl = *(const floatx8*)(cb + dl);
            floatx8 ch = *(const floatx8*)(cb + dh);
            floatx8 sl = *(const floatx8*)(sb + dl);
            floatx8 sh = *(const floatx8*)(sb + dh);
            floatx8 wl = *(const floatx8*)(wp + dl);
            floatx8 wh = *(const floatx8*)(wp + dh);
            half8 nl, nh;
#pragma unroll
            for (int j = 0; j < 8; ++j) {
                const float xl = (float)qf[kk][j] * inv * wl[j];
                const float xh = (float)qf[kk + 4][j] * inv * wh[j];
                nl[j] = (f16)(xl * cl[j] - xh * sl[j]);
                nh[j] = (f16)(xh * ch[j] + xl * sh[j]);
            }
            qf[kk] = nl;
            qf[kk + 4] = nh;
        }
    }

    floatx4 o[16];
#pragma unroll
    for (int i = 0; i < 16; ++i) o[i] = (floatx4){0.f, 0.f, 0.f, 0.f};
    float mrow[4] = {-1e30f, -1e30f, -1e30f, -1e30f};
    float lrow[4] = {0.f, 0.f, 0.f, 0.f};

    const size_t kbase = (size_t)(b * KV_ + kvh) * S_ * HD_;
    const size_t vbase = (size_t)(b * KV_ + kvh) * HD_ * S_;
    const int srow0 = qt * 128 + w * 16 + q4 * 4;

    const int kt_lo = (2 * qt - 8) > 0 ? (2 * qt - 8) : 0;
    const int kt_hi = 2 * qt + 1;
    const int s_lo_w = qt * 128 + w * 16;
    int ktw_lo = (s_lo_w - (WINDOW_ - 1)) >> 6;
    if (ktw_lo < kt_lo) ktw_lo = kt_lo;
    const int ktw_hi = (s_lo_w + 15) >> 6;

    auto stage = [&](int kt, int buf) {
#pragma unroll
        for (int c = 0; c < 4; ++c) {
            const int chunk = w * 4 + c;
            const int keyl = chunk * 2 + (lane >> 5);
            const int g = (lane & 31) ^ (keyl & 31);
            GLOAD_LDS16(Kh + kbase + (size_t)(kt * 64 + keyl) * HD_ + g * 8,
                        sK[buf] + chunk * 512 + lane * 8);
            const int diml = chunk * 8 + (lane >> 3);
            const int g2 = (lane & 7) ^ (diml & 7);
            GLOAD_LDS16(Vt + vbase + (size_t)diml * S_ + kt * 64 + g2 * 8,
                        sV[buf] + chunk * 512 + lane * 8);
        }
    };

    stage(kt_lo, 0);
    int cur = 0;
    for (int kt = kt_lo; kt <= kt_hi; ++kt, cur ^= 1) {
        __syncthreads();
        if (kt < kt_hi) stage(kt + 1, cur ^ 1);
        if (kt < ktw_lo || kt > ktw_hi) continue;

        const f16* sKc = sK[cur];
        const f16* sVc = sV[cur];

        floatx4 sc[4];
#pragma unroll
        for (int nt = 0; nt < 4; ++nt) sc[nt] = (floatx4){0.f, 0.f, 0.f, 0.f};
#pragma unroll
        for (int ks = 0; ks < 8; ++ks)
#pragma unroll
            for (int nt = 0; nt < 4; ++nt) {
                const int keyl = nt * 16 + i16;
                const int gp = (ks * 4 + q4) ^ (keyl & 31);
                half8 kf = *(const half8*)(sKc + keyl * 256 + gp * 8);
                sc[nt] = __builtin_amdgcn_mfma_f32_16x16x32_f16(qf[ks], kf, sc[nt], 0, 0, 0);
            }

#pragma unroll
        for (int r = 0; r < 4; ++r) {
            const int s = srow0 + r;
            float mx = -1e30f;
#pragma unroll
            for (int nt = 0; nt < 4; ++nt) {
                const int j = kt * 64 + nt * 16 + i16;
                const bool valid = (j <= s) && (s - j < WINDOW_);
                const float v = valid ? sc[nt][r] : MASKV_;
                sc[nt][r] = v;
                mx = fmaxf(mx, v);
            }
#pragma unroll
            for (int off = 1; off < 16; off <<= 1) mx = fmaxf(mx, __shfl_xor(mx, off));
            // exact defer-rescale: only when a NEW row-max appears
            if (mx > mrow[r]) {
                const float alpha = __expf(mrow[r] - mx);
                mrow[r] = mx;
                lrow[r] *= alpha;
#pragma unroll
                for (int nt2 = 0; nt2 < 16; ++nt2) o[nt2][r] *= alpha;
            }
            const float mnew = mrow[r];
            float rs = 0.f;
#pragma unroll
            for (int nt = 0; nt < 4; ++nt) {
                const float p = __expf(sc[nt][r] - mnew);
                sc[nt][r] = p;
                rs += p;
            }
#pragma unroll
            for (int off = 1; off < 16; off <<= 1) rs += __shfl_xor(rs, off);
            lrow[r] += rs;
        }

        f16* sPw = sP[w];
#pragma unroll
        for (int nt = 0; nt < 4; ++nt)
#pragma unroll
            for (int r = 0; r < 4; ++r)
                sPw[(q4 * 4 + r) * 72 + nt * 16 + i16] = (f16)sc[nt][r];
        asm volatile("s_waitcnt lgkmcnt(0)" ::: "memory");

#pragma unroll
        for (int kt2 = 0; kt2 < 2; ++kt2) {
            half8 pf = *(const half8*)(sPw + i16 * 72 + kt2 * 32 + q4 * 8);
#pragma unroll
            for (int nt2 = 0; nt2 < 16; ++nt2) {
                const int dim = nt2 * 16 + i16;
                const int gp = (kt2 * 4 + q4) ^ (dim & 7);
                half8 vf = *(const half8*)(sVc + dim * 64 + gp * 8);
                o[nt2] = __builtin_amdgcn_mfma_f32_16x16x32_f16(pf, vf, o[nt2], 0, 0, 0);
            }
        }
    }

    float inv2[4];
#pragma unroll
    for (int r = 0; r < 4; ++r) inv2[r] = 1.0f / lrow[r];
    f16* ob = attnh + (size_t)(b * S_ + qt * 128 + w * 16) * (H_ * HD_) + h * HD_;
#pragma unroll
    for (int nt2 = 0; nt2 < 16; ++nt2)
#pragma unroll
        for (int r = 0; r < 4; ++r)
            ob[(size_t)(q4 * 4 + r) * (H_ * HD_) + nt2 * 16 + i16] =
                (f16)(o[nt2][r] * inv2[r]);
}

// ---------------------------------------------------------------------------
extern "C" void kernel_launch(void* const* d_in, const int* in_sizes, int n_in,
                              void* d_out, int out_size, void* d_ws, size_t ws_size,
                              hipStream_t stream) {
    const float* x    = (const float*)d_in[0];
    const float* cosb = (const float*)d_in[1];
    const float* sinb = (const float*)d_in[2];
    const float* wq = (const float*)d_in[4];
    const float* wk = (const float*)d_in[5];
    const float* wv = (const float*)d_in[6];
    const float* wo = (const float*)d_in[7];
    const float* qw = (const float*)d_in[8];
    const float* kw = (const float*)d_in[9];
    float* out = (float*)d_out;

    f16* ws = (f16*)d_ws;
    f16* xh    = ws;                       // 8388608 (aliased as attnh later)
    f16* BT    = xh + 8388608;             // 6291456  [3072][2048]
    f16* woT   = BT + 6291456;             // 4194304  [2048][2048]
    f16* QKVh  = woT + 4194304;            // 12582912 [4096][3072]
    f16* Kh    = QKVh + 12582912;          // 2097152
    f16* Vt    = Kh + 2097152;             // 2097152
    f16* attnh = xh;                       // alias: xh dead after QKV GEMM

    const int M = B_ * S_;  // 4096

    // 1) convert x + transpose all weights (one dispatch)
    prep<<<8192 + 2560, 256, 0, stream>>>(x, wq, wk, wv, wo, xh, BT, woT);

    // 2) fused QKV projection: [4096][2048] @ [3072][2048]^T
    //    round-0 2-phase 128x128 + XCD-chunked swizzle (768 = 96/XCD)
    gemm_f16<f16><<<768, 256, 0, stream>>>(xh, BT, QKVh, M, 3072, D_, 24);

    // 3) K norm+rope -> Kh, V norm+transpose -> Vt (Q fused into attn)
    norm_kv_f16<<<NRBK_ + 128, 256, 0, stream>>>(QKVh, Kh, Vt, cosb, sinb, kw);

    // 4) flash attention (fused Q norm+rope, dbuf staging, defer-rescale)
    attn_mfma<<<dim3(S_ / 128, H_, B_), 512, 0, stream>>>(QKVh, Kh, Vt, attnh,
                                                          cosb, sinb, qw);

    // 5) output projection (2-phase 128x128 + XCD swizzle, fp32 out)
    gemm_f16<float><<<512, 256, 0, stream>>>(attnh, woT, out, M, D_, H_ * HD_, 16);
}